// Round 10
// baseline (300.493 us; speedup 1.0000x reference)
//
#include <hip/hip_runtime.h>
#include <hip/hip_bf16.h>
#include <stdint.h>

#define HEADS 16
#define DIMH 64
#define SEGL 512
#define NPM 16
#define NB 2
#define NS 4096
#define ND 1024
#define NW 8
#define NBW 16
#define KVLEN 528
#define NQKV 3072
#define MROWS 8192
#define RMS_EPS 1.1920928955078125e-07f

typedef __attribute__((ext_vector_type(8))) short bf16x8;
typedef __attribute__((ext_vector_type(4))) float f32x4;
typedef __attribute__((ext_vector_type(8))) unsigned short u16x8;

union FragU { bf16x8 v; uint64_t q[2]; unsigned short u[8]; };

__device__ inline unsigned short f2bf(float x){
  __hip_bfloat16 b = __float2bfloat16(x);
  return __builtin_bit_cast(unsigned short, b);
}

__device__ inline f32x4 mfma16(bf16x8 a, bf16x8 b, f32x4 c){
  return __builtin_amdgcn_mfma_f32_16x16x32_bf16(a, b, c, 0, 0, 0);
}

// async global->LDS, 16B per lane; LDS dest = wave-uniform base + lane*16
__device__ __forceinline__ void gl_lds16(const unsigned short* g, unsigned short* l){
  __builtin_amdgcn_global_load_lds(
    (const __attribute__((address_space(1))) unsigned int*)g,
    (__attribute__((address_space(3))) unsigned int*)l, 16, 0, 0);
}

// stage one wave's 32 rows (16B/lane per inst) of A and B K-chunks (2-phase GEMM)
__device__ __forceinline__ void stage4(const unsigned short* gA, const unsigned short* gB,
                                       unsigned short* sA, unsigned short* sB, size_t row16){
  gl_lds16(gA,         sA);
  gl_lds16(gA + row16, sA + 512);
  gl_lds16(gB,         sB);
  gl_lds16(gB + row16, sB + 512);
}

// ---------------- rope table ----------------
__global__ void rope_table_k(float* __restrict__ cosT, float* __restrict__ sinT){
  int id = blockIdx.x*256 + threadIdx.x;
  if (id >= NS*32) return;
  int p = id & 31, s = id >> 5;
  float inv = powf(10000.0f, -(float)p * (1.0f/32.0f));
  float a = (float)s * inv;
  cosT[id] = cosf(a);
  sinT[id] = sinf(a);
}

// ---------------- rmsnorm + cast ----------------
__global__ __launch_bounds__(256) void rmsnorm_k(const float* __restrict__ seq, const float* __restrict__ nw,
                                                 unsigned short* __restrict__ xo){
  int r = blockIdx.x, t = threadIdx.x;
  const float4 v = ((const float4*)(seq + (size_t)r*ND))[t];
  float ss = v.x*v.x + v.y*v.y + v.z*v.z + v.w*v.w;
  #pragma unroll
  for (int off=32; off; off>>=1) ss += __shfl_xor(ss, off);
  __shared__ float red[4];
  if ((t&63)==0) red[t>>6] = ss;
  __syncthreads();
  float scale = rsqrtf((red[0]+red[1]+red[2]+red[3])*(1.0f/(float)ND) + RMS_EPS);
  const float4 w = ((const float4*)nw)[t];
  ushort4 o;
  o.x = f2bf(v.x*scale*w.x);
  o.y = f2bf(v.y*scale*w.y);
  o.z = f2bf(v.z*scale*w.z);
  o.w = f2bf(v.w*scale*w.w);
  ((ushort4*)xo)[(size_t)r*256 + t] = o;
}

// ---------------- transpose + cast weights ----------------
__global__ __launch_bounds__(256) void tcast_k(const float* __restrict__ in, unsigned short* __restrict__ out,
                                               int R, int C){
  __shared__ float tile[32][33];
  int c0 = blockIdx.x*32, r0 = blockIdx.y*32;
  int tx = threadIdx.x & 31, ty = threadIdx.x >> 5;
  #pragma unroll
  for (int i=0;i<4;i++) tile[ty+8*i][tx] = in[(size_t)(r0+ty+8*i)*C + c0+tx];
  __syncthreads();
  #pragma unroll
  for (int i=0;i<4;i++) out[(size_t)(c0+ty+8*i)*R + r0+tx] = f2bf(tile[tx][ty+8*i]);
}

// ---------------- pmem prefix fill ----------------
__global__ void pmem_fill_k(const float* __restrict__ pmem, unsigned short* __restrict__ Kb,
                            unsigned short* __restrict__ VbT){
  int id = blockIdx.x*256 + threadIdx.x;
  if (id >= NBW*HEADS*NPM*DIMH) return;
  int d = id & 63, j = (id>>6)&15, h = (id>>10)&15, bw = id>>14;
  size_t srcK = ((size_t)h*NPM + j)*DIMH + d;
  Kb[((size_t)(bw*HEADS+h)*KVLEN + j)*DIMH + d] = f2bf(pmem[srcK]);
  VbT[((size_t)(bw*HEADS+h)*DIMH + d)*KVLEN + j] = f2bf(pmem[(size_t)HEADS*NPM*DIMH + srcK]);
}

// ---------------- Vb[bwh][512][64] -> VbT[bwh][64][528] ----------------
__global__ __launch_bounds__(256) void vtrans_k(const unsigned short* __restrict__ Vb,
                                                unsigned short* __restrict__ VbT){
  __shared__ unsigned short T[64][72];
  int jt = blockIdx.x, bwh = blockIdx.y, t = threadIdx.x;
  int r = t>>2, c = t&3;
  int j0 = jt*64;
  const unsigned short* src = Vb + ((size_t)bwh*512 + j0 + r)*DIMH + c*16;
  *(u16x8*)&T[r][c*16]     = *(const u16x8*)(src);
  *(u16x8*)&T[r][c*16 + 8] = *(const u16x8*)(src + 8);
  __syncthreads();
  u16x8 outv, outv2;
  #pragma unroll
  for (int k=0;k<8;k++) outv[k] = T[c*16+k][r];
  #pragma unroll
  for (int k=0;k<8;k++) outv2[k] = T[c*16+8+k][r];
  *(u16x8*)&VbT[((size_t)bwh*DIMH + r)*KVLEN + NPM + j0 + c*16] = outv;
  *(u16x8*)&VbT[((size_t)bwh*DIMH + r)*KVLEN + NPM + j0 + c*16 + 8] = outv2;
}

// ================= qkv GEMM: phase-pipelined, counted-vmcnt, tri-buffer =================
// BM=128, BN=256, BK=64. 512 threads = 8 waves (2M x 4N), per-wave 64x64 output.
// LDS: 3 bufs x (A 128x64 + B 256x64) bf16 = 144 KB. XOR swizzle (lr&7)<<4 on 16B chunks.
// Tile t reads buf[t%3]; phases 0-2 of tile t stage tile t+2 into buf[(t+2)%3].
// End-of-tile wait: vmcnt(6) (tile t+2's 6 loads stay in flight) -> tile t+1 landed.
#define QNT 16  // 1024/64

__global__ __launch_bounds__(512) void gemm_qkv8_k(const unsigned short* __restrict__ A,
    const unsigned short* __restrict__ Bt,
    unsigned short* __restrict__ Qb, unsigned short* __restrict__ Kb, unsigned short* __restrict__ Vb,
    float* __restrict__ origv, const float* __restrict__ cosT, const float* __restrict__ sinT){
  const int K = 1024;
  __shared__ __align__(16) unsigned short As[3*128*64];  // 3 x 8192 shorts
  __shared__ __align__(16) unsigned short Bs[3*256*64];  // 3 x 16384 shorts
  int t0 = threadIdx.x; int lane = t0&63; int wv = t0>>6;
  int lr = lane&15, lg = lane>>4;
  int wm = wv>>2, wn = wv&3;
  int m0 = blockIdx.y*128, n0 = blockIdx.x*256;
  int swz = (lr&7)<<4;

  f32x4 acc[4][4];
  f32x4 z = {0.f,0.f,0.f,0.f};
  #pragma unroll
  for (int i=0;i<4;i++)
    #pragma unroll
    for (int j=0;j<4;j++) acc[i][j] = z;

  // staging: lane l covers row (wv*8 + (l>>3) + 64n), 16B chunk (l&7), source pre-swizzled
  int rbase = wv*8 + (lane>>3);
  int kcs = ((lane&7)*8) ^ (((lane>>3)&7)*8);   // swizzled k-chunk (shorts)
  const unsigned short* gA = A  + (size_t)(m0 + rbase)*K + kcs;
  const unsigned short* gB = Bt + (size_t)(n0 + rbase)*K + kcs;
  unsigned short* dA = As + wv*512;
  unsigned short* dB = Bs + wv*512;

#define SG_A(T_, BF_)  { gl_lds16(gA + (size_t)(T_)*64,               dA + (BF_)*8192); \
                         gl_lds16(gA + (size_t)64*K  + (size_t)(T_)*64, dA + (BF_)*8192 + 4096); }
#define SG_B01(T_, BF_){ gl_lds16(gB + (size_t)(T_)*64,               dB + (BF_)*16384); \
                         gl_lds16(gB + (size_t)64*K  + (size_t)(T_)*64, dB + (BF_)*16384 + 4096); }
#define SG_B23(T_, BF_){ gl_lds16(gB + (size_t)128*K + (size_t)(T_)*64, dB + (BF_)*16384 + 8192); \
                         gl_lds16(gB + (size_t)192*K + (size_t)(T_)*64, dB + (BF_)*16384 + 12288); }

  // prologue: tiles 0 and 1 (6 loads each); wait tile0 (6 newest stay in flight)
  SG_A(0,0); SG_B01(0,0); SG_B23(0,0);
  SG_A(1,1); SG_B01(1,1); SG_B23(1,1);
  asm volatile("s_waitcnt vmcnt(6)" ::: "memory");
  __builtin_amdgcn_s_barrier();
  __builtin_amdgcn_sched_barrier(0);

#define PH(MI, MJ, STAGE, TAILVM) do { \
    FragU a_[2][2], b_[2][2]; \
    _Pragma("unroll") \
    for (int x=0;x<2;x++){ \
      const char* pa = rA + (size_t)(wm*64 + (MI+x)*16 + lr)*128; \
      const char* pb = rB + (size_t)(wn*64 + (MJ+x)*16 + lr)*128; \
      _Pragma("unroll") \
      for (int ks=0;ks<2;ks++){ \
        a_[x][ks].q[0] = *(const uint64_t*)(pa + ((ks*64      + lg*8) ^ swz)); \
        a_[x][ks].q[1] = *(const uint64_t*)(pa + ((ks*64 + 32 + lg*8) ^ swz)); \
        b_[x][ks].q[0] = *(const uint64_t*)(pb + ((ks*64      + lg*8) ^ swz)); \
        b_[x][ks].q[1] = *(const uint64_t*)(pb + ((ks*64 + 32 + lg*8) ^ swz)); \
      } \
    } \
    STAGE; \
    __builtin_amdgcn_s_barrier(); \
    __builtin_amdgcn_sched_barrier(0); \
    __builtin_amdgcn_s_setprio(1); \
    _Pragma("unroll") \
    for (int x=0;x<2;x++) \
      _Pragma("unroll") \
      for (int y=0;y<2;y++) \
        _Pragma("unroll") \
        for (int ks=0;ks<2;ks++) \
          acc[MI+x][MJ+y] = mfma16(a_[x][ks].v, b_[y][ks].v, acc[MI+x][MJ+y]); \
    __builtin_amdgcn_s_setprio(0); \
    TAILVM; \
    __builtin_amdgcn_s_barrier(); \
    __builtin_amdgcn_sched_barrier(0); \
  } while(0)

  for (int t=0; t<QNT; ++t){
    const char* rA = (const char*)(As + (t%3)*8192);
    const char* rB = (const char*)(Bs + (t%3)*16384);
    int b2 = (t+2)%3;
    bool st = (t+2) < QNT;
    PH(0,0, if(st){SG_A(t+2,b2);}, );
    PH(0,2, if(st){SG_B01(t+2,b2);}, );
    PH(2,0, if(st){SG_B23(t+2,b2);}, );
    if (t < QNT-2){
      PH(2,2, , { __builtin_amdgcn_sched_barrier(0); asm volatile("s_waitcnt vmcnt(6)" ::: "memory"); });
    } else if (t == QNT-2){
      PH(2,2, , { __builtin_amdgcn_sched_barrier(0); asm volatile("s_waitcnt vmcnt(0)" ::: "memory"); });
    } else {
      PH(2,2, , );
    }
  }
#undef PH
#undef SG_A
#undef SG_B01
#undef SG_B23

  // epilogue: identical math to verified MODE-1 path (row/col formulas adapted to wave geometry)
  #pragma unroll
  for (int i=0;i<4;i++){
    #pragma unroll
    for (int j=0;j<4;j++){
      int col  = n0 + wn*64 + j*16 + lr;
      int rowb = m0 + wm*64 + i*16 + lg*4;
      if (col < 2048){
        #pragma unroll
        for (int e=0;e<4;e++){
          int row = rowb + e;
          float val = acc[i][j][e];
          float partner = __shfl_xor(val, 1);
          int s = row&4095;
          int w = s>>9, ii = s&511, bwi = (row>>12)*8 + w;
          int hh = (col>>6)&15, dh = col&63;
          int fp = dh>>1;
          float cs = cosT[s*32+fp], sn = sinT[s*32+fp];
          float rot = (col&1) ? fmaf(val,cs, partner*sn) : fmaf(val,cs, -partner*sn);
          if (col < 1024) Qb[((size_t)(bwi*HEADS+hh)*SEGL + ii)*DIMH + dh] = f2bf(rot);
          else            Kb[((size_t)(bwi*HEADS+hh)*KVLEN + NPM + ii)*DIMH + dh] = f2bf(rot);
        }
      } else {
        #pragma unroll
        for (int e=0;e<4;e++){
          int row = rowb + e;
          float val = acc[i][j][e];
          int s = row&4095;
          int w = s>>9, ii = s&511, bwi = (row>>12)*8 + w;
          int hh = (col>>6)&15, dh = col&63;
          Vb[((size_t)(bwi*HEADS+hh)*512 + ii)*DIMH + dh] = f2bf(val);
          origv[((size_t)((row>>12)*HEADS+hh)*NS + s)*DIMH + dh] = val;
        }
      }
    }
  }
}

// ---------------- 2-phase GEMM body (kept for out-proj) ----------------
__global__ __launch_bounds__(256) void gemm_out_k(const unsigned short* __restrict__ A,
    const unsigned short* __restrict__ Bt, float* __restrict__ Cf){
  const int M = MROWS, N = 1024, K = 1024;
  __shared__ __align__(16) unsigned short As[2][4096];
  __shared__ __align__(16) unsigned short Bs[2][4096];
  int t = threadIdx.x; int lane = t&63; int wv = t>>6; int lr = lane&15; int lg = lane>>4;
  int wm = wv>>1, wn = wv&1;
  int m0 = blockIdx.y*128, n0 = blockIdx.x*128;

  f32x4 acc[4][4];
  f32x4 z = {0.f,0.f,0.f,0.f};
  #pragma unroll
  for (int i=0;i<4;i++)
    #pragma unroll
    for (int j=0;j<4;j++) acc[i][j] = z;

  const unsigned short* gA = A  + (size_t)(m0 + wv*32 + (lane>>2))*K + (lane&3)*8;
  const unsigned short* gB = Bt + (size_t)(n0 + wv*32 + (lane>>2))*K + (lane&3)*8;
  const size_t row16 = (size_t)16*K;

  int aoff[4], boff[4];
  #pragma unroll
  for (int i=0;i<4;i++){
    aoff[i] = (wm*64 + i*16 + lr)*64 + lg*16;
    boff[i] = (wn*64 + i*16 + lr)*64 + lg*16;
  }

  stage4(gA, gB, As[0] + wv*1024, Bs[0] + wv*1024, row16);
  __syncthreads();

  int cur = 0;
  for (int k0=0; k0<K; k0+=32){
    int nk = k0 + 32;
    if (nk < K)
      stage4(gA + nk, gB + nk, As[cur^1] + wv*1024, Bs[cur^1] + wv*1024, row16);
    const char* AsB = (const char*)As[cur];
    const char* BsB = (const char*)Bs[cur];
    bf16x8 af[4], bfr[4];
    #pragma unroll
    for (int i=0;i<4;i++){
      af[i]  = *(const bf16x8*)(AsB + aoff[i]);
      bfr[i] = *(const bf16x8*)(BsB + boff[i]);
    }
    #pragma unroll
    for (int i=0;i<4;i++)
      #pragma unroll
      for (int j=0;j<4;j++)
        acc[i][j] = mfma16(af[i], bfr[j], acc[i][j]);
    __syncthreads();
    cur ^= 1;
  }

  #pragma unroll
  for (int i=0;i<4;i++)
    #pragma unroll
    for (int j=0;j<4;j++)
      #pragma unroll
      for (int e=0;e<4;e++){
        int row = m0 + wm*64 + i*16 + lg*4 + e;
        int col = n0 + wn*64 + j*16 + lr;
        Cf[(size_t)row*N + col] = acc[i][j][e];
      }
}

// ---------------- attention (unchanged from r9 passing build) ----------------
__global__ __launch_bounds__(256) void attn_k(const unsigned short* __restrict__ Qb,
    const unsigned short* __restrict__ Kb, const unsigned short* __restrict__ VbT,
    unsigned short* __restrict__ att){
  int qt = blockIdx.x, h = blockIdx.y, bw = blockIdx.z;
  int t = threadIdx.x, lane = t&63, wv = t>>6, lr = lane&15, lg = lane>>4;
  __shared__ __align__(16) unsigned short Ks[2][4096];
  __shared__ __align__(16) unsigned short Vs[2][4096];

  const unsigned short* Kbase = Kb  + (size_t)(bw*HEADS+h)*KVLEN*DIMH;
  const unsigned short* Vtb   = VbT + (size_t)(bw*HEADS+h)*DIMH*KVLEN;

  bf16x8 qf[2][2];
  #pragma unroll
  for (int ifr=0; ifr<2; ++ifr){
    const unsigned short* Qrow = Qb + ((size_t)((bw*HEADS+h)*SEGL) + qt*128 + wv*32 + ifr*16 + lr)*DIMH;
    #pragma unroll
    for (int kh=0; kh<2; ++kh){
      FragU f;
      f.q[0] = *(const uint64_t*)(Qrow + kh*32 + lg*4);
      f.q[1] = *(const uint64_t*)(Qrow + kh*32 + 16 + lg*4);
      qf[ifr][kh] = f.v;
    }
  }

  int rls[2], xsw[2];
  #pragma unroll
  for (int k2=0;k2<2;k2++){
    rls[k2] = wv*16 + k2*8 + (lane>>3);
    xsw[k2] = ((lane&7)*16) ^ ((rls[k2]&7)<<4);
  }

  #define STAGE_KV(buf, j0_) do { \
    int xm_ = ((j0_) == 512) ? 31 : 127; \
    _Pragma("unroll") \
    for (int k2=0;k2<2;k2++){ \
      int jr = (j0_) + rls[k2]; if (jr>527) jr=527; \
      gl_lds16((const unsigned short*)((const char*)Kbase + (size_t)jr*128 + xsw[k2]), \
               Ks[buf] + wv*1024 + k2*512); \
      gl_lds16((const unsigned short*)((const char*)Vtb + (size_t)rls[k2]*(KVLEN*2) + (size_t)(j0_)*2 + (xsw[k2] & xm_)), \
               Vs[buf] + wv*1024 + k2*512); \
    } \
  } while(0)

  const float NEG = -3.0e38f;
  float m[2]  = {NEG, NEG};
  float lsum[2] = {0.f, 0.f};
  f32x4 o[4][2];
  f32x4 z = {0.f,0.f,0.f,0.f};
  #pragma unroll
  for (int df=0; df<4; ++df){ o[df][0]=z; o[df][1]=z; }

  int ntiles = (qt*128 + 207)>>6; if (ntiles>9) ntiles=9;
  int swzK = (lr&7)<<4;

  STAGE_KV(0, 0);
  __syncthreads();

  int cur = 0;
  for (int jt=0; jt<ntiles; ++jt){
    int j0 = jt*64;
    if (jt+1 < ntiles) STAGE_KV(cur^1, j0+64);

    const char* KsB = (const char*)Ks[cur];
    f32x4 s[2][4];
    #pragma unroll
    for (int ifr=0; ifr<2; ++ifr)
      #pragma unroll
      for (int jf=0; jf<4; ++jf) s[ifr][jf] = z;
    #pragma unroll
    for (int jf=0; jf<4; ++jf){
      int rowb = (jf*16 + lr)*128;
      #pragma unroll
      for (int kh=0; kh<2; ++kh){
        FragU kf;
        kf.q[0] = *(const uint64_t*)(KsB + rowb + ((kh*64      + lg*8) ^ swzK));
        kf.q[1] = *(const uint64_t*)(KsB + rowb + ((kh*64 + 32 + lg*8) ^ swzK));
        s[0][jf] = mfma16(kf.v, qf[0][kh], s[0][jf]);
        s[1][jf] = mfma16(kf.v, qf[1][kh], s[1][jf]);
      }
    }

    float alpha[2];
    #pragma unroll
    for (int ifr=0; ifr<2; ++ifr){
      int iglob = qt*128 + wv*32 + ifr*16 + lr;
      float mt = NEG;
      #pragma unroll
      for (int jf=0; jf<4; ++jf){
        #pragma unroll
        for (int e=0;e<4;e++){
          int jl = j0 + jf*16 + lg*4 + e;
          bool ok = (jl < KVLEN) && (jl - NPM <= iglob);
          float v = ok ? s[ifr][jf][e]*0.125f : NEG;
          s[ifr][jf][e] = v;
          mt = fmaxf(mt, v);
        }
      }
      mt = fmaxf(mt, __shfl_xor(mt, 16));
      mt = fmaxf(mt, __shfl_xor(mt, 32));
      float mn = fmaxf(m[ifr], mt);
      alpha[ifr] = __expf(m[ifr]-mn);
      m[ifr] = mn;
      float ps = 0.f;
      #pragma unroll
      for (int jf=0; jf<4; ++jf){
        #pragma unroll
        for (int e=0;e<4;e++){
          float p = __expf(s[ifr][jf][e] - mn);
          s[ifr][jf][e] = p;
          ps += p;
        }
      }
      ps += __shfl_xor(ps, 16);
      ps += __shfl_xor(ps, 32);
      lsum[ifr] = lsum[ifr]*alpha[ifr] + ps;
    }

    bf16x8 pa[2][2];
    #pragma unroll
    for (int ifr=0; ifr<2; ++ifr){
      #pragma unroll
      for (int kh=0; kh<2; ++kh){
        FragU f;
        #pragma unroll
        for (int e=0;e<4;e++){
          f.u[e]   = f2bf(s[ifr][2*kh  ][e]);
          f.u[4+e] = f2bf(s[ifr][2*kh+1][e]);
        }
        pa[ifr][kh] = f.v;
      }
    }

    #pragma unroll
    for (int ifr=0; ifr<2; ++ifr){
      float ae[4];
      #pragma unroll
      for (int e=0;e<4;e++) ae[e] = __shfl(alpha[ifr], lg*4+e, 16);
      #pragma unroll
      for (int df=0; df<4; ++df)
        #pragma unroll
        for (int e=0;e<4;e++) o[df][ifr][e] *= ae[e];
    }

    const char* VsB = (const char*)Vs[cur];
    #pragma unroll
    for (int df=0; df<4; ++df){
      int vrow = (df*16 + lr)*128;
      FragU v0, v1;
      v0.q[0] = *(const uint64_t*)(VsB + vrow + ((      lg*8) ^ swzK));
      v0.q[1] = *(const uint64_t*)(VsB + vrow + ((32  + lg*8) ^ swzK));
      v1.q[0] = *(const uint64_t*)(VsB + vrow + ((64  + lg*8) ^ swzK));
      v1.q[1] = *(const uint64_t*)(VsB + vrow + ((96  + lg*8) ^ swzK));
      o[df][0] = mfma16(pa[0][0], v0.v, o[df][0]);
      o[df][0] = mfma16(pa[0][1], v1.v, o[df][0]);
      o[df][1] = mfma16(pa[1][0], v0.v, o[df][1]);
      o[df][1] = mfma16(pa[1][1], v1.v, o[df][1]);
    }

    __syncthreads();
    cur ^= 1;
  }

  #pragma unroll
  for (int ifr=0; ifr<2; ++ifr){
    float inv = 1.0f / lsum[ifr];
    float il[4];
    #pragma unroll
    for (int e=0;e<4;e++) il[e] = __shfl(inv, lg*4+e, 16);
    #pragma unroll
    for (int e=0;e<4;e++){
      int row = bw*SEGL + qt*128 + wv*32 + ifr*16 + lg*4 + e;
      #pragma unroll
      for (int df=0; df<4; ++df)
        att[(size_t)row*1024 + h*64 + df*16 + lr] = f2bf(o[df][ifr][e]*il[e]);
    }
  }
  #undef STAGE_KV
}

extern "C" void kernel_launch(void* const* d_in, const int* in_sizes, int n_in,
                              void* d_out, int out_size, void* d_ws, size_t ws_size,
                              hipStream_t stream) {
  const float* seq  = (const float*)d_in[0];
  const float* nw   = (const float*)d_in[1];
  const float* wqkv = (const float*)d_in[2];
  const float* wout = (const float*)d_in[3];
  const float* pmem = (const float*)d_in[4];
  float* out0  = (float*)d_out;
  float* origv = out0 + (size_t)MROWS*ND;

  char* ws = (char*)d_ws;
  unsigned short* xbf   = (unsigned short*)(ws + 0);          // 16,777,216
  unsigned short* wqkvT = (unsigned short*)(ws + 16777216);   //  6,291,456
  unsigned short* woutT = (unsigned short*)(ws + 23068672);   //  2,097,152
  float*          cosT  = (float*)(ws + 25165824);            //    524,288
  float*          sinT  = (float*)(ws + 25690112);            //    524,288
  unsigned short* Qb    = (unsigned short*)(ws + 26214400);   // 16,777,216
  unsigned short* Kb    = (unsigned short*)(ws + 42991616);   // 17,301,504
  unsigned short* VbT   = (unsigned short*)(ws + 60293120);   // 17,301,504 ([bwh][64][528])
  unsigned short* att   = (unsigned short*)(ws + 77594624);   // 16,777,216
  unsigned short* Vb    = att;  // [bwh][512][64] temp; dead before attn writes att

  rope_table_k<<<dim3(512), dim3(256), 0, stream>>>(cosT, sinT);
  rmsnorm_k<<<dim3(MROWS), dim3(256), 0, stream>>>(seq, nw, xbf);
  tcast_k<<<dim3(NQKV/32, 1024/32), dim3(256), 0, stream>>>(wqkv, wqkvT, 1024, NQKV);
  tcast_k<<<dim3(1024/32, 1024/32), dim3(256), 0, stream>>>(wout, woutT, 1024, 1024);
  pmem_fill_k<<<dim3(1024), dim3(256), 0, stream>>>(pmem, Kb, VbT);
  gemm_qkv8_k<<<dim3(NQKV/256, MROWS/128), dim3(512), 0, stream>>>(
      xbf, wqkvT, Qb, Kb, Vb, origv, cosT, sinT);
  vtrans_k<<<dim3(8, NBW*HEADS), dim3(256), 0, stream>>>(Vb, VbT);
  attn_k<<<dim3(4, 16, 16), dim3(256), 0, stream>>>(Qb, Kb, VbT, att);
  gemm_out_k<<<dim3(1024/128, MROWS/128), dim3(256), 0, stream>>>(att, woutT, out0);
}

// Round 11
// 242.181 us; speedup vs baseline: 1.2408x; 1.2408x over previous
//
#include <hip/hip_runtime.h>
#include <hip/hip_bf16.h>
#include <stdint.h>

#define HEADS 16
#define DIMH 64
#define SEGL 512
#define NPM 16
#define NB 2
#define NS 4096
#define ND 1024
#define NW 8
#define NBW 16
#define KVLEN 528
#define NQKV 3072
#define MROWS 8192
#define RMS_EPS 1.1920928955078125e-07f

typedef __attribute__((ext_vector_type(8))) short bf16x8;
typedef __attribute__((ext_vector_type(4))) float f32x4;
typedef __attribute__((ext_vector_type(8))) unsigned short u16x8;

union FragU { bf16x8 v; uint64_t q[2]; unsigned short u[8]; };

__device__ inline unsigned short f2bf(float x){
  __hip_bfloat16 b = __float2bfloat16(x);
  return __builtin_bit_cast(unsigned short, b);
}

__device__ inline f32x4 mfma16(bf16x8 a, bf16x8 b, f32x4 c){
  return __builtin_amdgcn_mfma_f32_16x16x32_bf16(a, b, c, 0, 0, 0);
}

// async global->LDS, 16B per lane; LDS dest = wave-uniform base + lane*16
__device__ __forceinline__ void gl_lds16(const unsigned short* g, unsigned short* l){
  __builtin_amdgcn_global_load_lds(
    (const __attribute__((address_space(1))) unsigned int*)g,
    (__attribute__((address_space(3))) unsigned int*)l, 16, 0, 0);
}

// stage one wave's 32 rows (16B/lane per inst) of A and B K-chunks
__device__ __forceinline__ void stage4(const unsigned short* gA, const unsigned short* gB,
                                       unsigned short* sA, unsigned short* sB, size_t row16){
  gl_lds16(gA,         sA);
  gl_lds16(gA + row16, sA + 512);
  gl_lds16(gB,         sB);
  gl_lds16(gB + row16, sB + 512);
}

// ---------------- rope table ----------------
__global__ void rope_table_k(float* __restrict__ cosT, float* __restrict__ sinT){
  int id = blockIdx.x*256 + threadIdx.x;
  if (id >= NS*32) return;
  int p = id & 31, s = id >> 5;
  float inv = powf(10000.0f, -(float)p * (1.0f/32.0f));
  float a = (float)s * inv;
  cosT[id] = cosf(a);
  sinT[id] = sinf(a);
}

// ---------------- rmsnorm + cast ----------------
__global__ __launch_bounds__(256) void rmsnorm_k(const float* __restrict__ seq, const float* __restrict__ nw,
                                                 unsigned short* __restrict__ xo){
  int r = blockIdx.x, t = threadIdx.x;
  const float4 v = ((const float4*)(seq + (size_t)r*ND))[t];
  float ss = v.x*v.x + v.y*v.y + v.z*v.z + v.w*v.w;
  #pragma unroll
  for (int off=32; off; off>>=1) ss += __shfl_xor(ss, off);
  __shared__ float red[4];
  if ((t&63)==0) red[t>>6] = ss;
  __syncthreads();
  float scale = rsqrtf((red[0]+red[1]+red[2]+red[3])*(1.0f/(float)ND) + RMS_EPS);
  const float4 w = ((const float4*)nw)[t];
  ushort4 o;
  o.x = f2bf(v.x*scale*w.x);
  o.y = f2bf(v.y*scale*w.y);
  o.z = f2bf(v.z*scale*w.z);
  o.w = f2bf(v.w*scale*w.w);
  ((ushort4*)xo)[(size_t)r*256 + t] = o;
}

// ---------------- transpose + cast weights ----------------
__global__ __launch_bounds__(256) void tcast_k(const float* __restrict__ in, unsigned short* __restrict__ out,
                                               int R, int C){
  __shared__ float tile[32][33];
  int c0 = blockIdx.x*32, r0 = blockIdx.y*32;
  int tx = threadIdx.x & 31, ty = threadIdx.x >> 5;
  #pragma unroll
  for (int i=0;i<4;i++) tile[ty+8*i][tx] = in[(size_t)(r0+ty+8*i)*C + c0+tx];
  __syncthreads();
  #pragma unroll
  for (int i=0;i<4;i++) out[(size_t)(c0+ty+8*i)*R + r0+tx] = f2bf(tile[tx][ty+8*i]);
}

// ---------------- pmem prefix fill ----------------
__global__ void pmem_fill_k(const float* __restrict__ pmem, unsigned short* __restrict__ Kb,
                            unsigned short* __restrict__ VbT){
  int id = blockIdx.x*256 + threadIdx.x;
  if (id >= NBW*HEADS*NPM*DIMH) return;
  int d = id & 63, j = (id>>6)&15, h = (id>>10)&15, bw = id>>14;
  size_t srcK = ((size_t)h*NPM + j)*DIMH + d;
  Kb[((size_t)(bw*HEADS+h)*KVLEN + j)*DIMH + d] = f2bf(pmem[srcK]);
  VbT[((size_t)(bw*HEADS+h)*DIMH + d)*KVLEN + j] = f2bf(pmem[(size_t)HEADS*NPM*DIMH + srcK]);
}

// ---------------- Vb[bwh][512][64] -> VbT[bwh][64][528] ----------------
__global__ __launch_bounds__(256) void vtrans_k(const unsigned short* __restrict__ Vb,
                                                unsigned short* __restrict__ VbT){
  __shared__ unsigned short T[64][72];
  int jt = blockIdx.x, bwh = blockIdx.y, t = threadIdx.x;
  int r = t>>2, c = t&3;
  int j0 = jt*64;
  const unsigned short* src = Vb + ((size_t)bwh*512 + j0 + r)*DIMH + c*16;
  *(u16x8*)&T[r][c*16]     = *(const u16x8*)(src);
  *(u16x8*)&T[r][c*16 + 8] = *(const u16x8*)(src + 8);
  __syncthreads();
  u16x8 outv, outv2;
  #pragma unroll
  for (int k=0;k<8;k++) outv[k] = T[c*16+k][r];
  #pragma unroll
  for (int k=0;k<8;k++) outv2[k] = T[c*16+8+k][r];
  *(u16x8*)&VbT[((size_t)bwh*DIMH + r)*KVLEN + NPM + j0 + c*16] = outv;
  *(u16x8*)&VbT[((size_t)bwh*DIMH + r)*KVLEN + NPM + j0 + c*16 + 8] = outv2;
}

// ---------------- GEMM body: 2-phase structure + T4 counted-vmcnt, 4-buf, prefetch-3 ----------------
// 128x128 tile, BK=32, 4 waves. Tile t reads buf[t&3]; iter t stages tile t+3 into buf[(t+3)&3]
// (= buf[(t-1)&3], safe: its readers passed the end-of-(t-1) barrier).
// End-of-iter wait: vmcnt(8) keeps tiles t+2,t+3 (4 loads each) in flight; tile t+1 landed.
// Raw s_barrier (no vmcnt drain) + sched_barrier(0) ordering fence.
// MODE 0: write f32 C. MODE 1: fused qkv epilogue (rope + scatter; V row-major + origv).
template<int MODE>
__device__ __forceinline__ void gemm_body(const unsigned short* __restrict__ A,
    const unsigned short* __restrict__ Bt, float* __restrict__ Cf,
    unsigned short* __restrict__ Qb, unsigned short* __restrict__ Kb, unsigned short* __restrict__ Vb,
    float* __restrict__ origv, const float* __restrict__ cosT, const float* __restrict__ sinT,
    int N, int K){
  __shared__ __align__(16) unsigned short As[4][4096];  // [buf][128][32]
  __shared__ __align__(16) unsigned short Bs[4][4096];
  int t0 = threadIdx.x; int lane = t0&63; int wv = t0>>6; int lr = lane&15; int lg = lane>>4;
  int wm = wv>>1, wn = wv&1;
  int m0 = blockIdx.y*128, n0 = blockIdx.x*128;

  f32x4 acc[4][4];
  f32x4 z = {0.f,0.f,0.f,0.f};
  #pragma unroll
  for (int i=0;i<4;i++)
    #pragma unroll
    for (int j=0;j<4;j++) acc[i][j] = z;

  const unsigned short* gA = A  + (size_t)(m0 + wv*32 + (lane>>2))*K + (lane&3)*8;
  const unsigned short* gB = Bt + (size_t)(n0 + wv*32 + (lane>>2))*K + (lane&3)*8;
  const size_t row16 = (size_t)16*K;

  int aoff[4], boff[4];
  #pragma unroll
  for (int i=0;i<4;i++){
    aoff[i] = (wm*64 + i*16 + lr)*64 + lg*16;
    boff[i] = (wn*64 + i*16 + lr)*64 + lg*16;
  }

  const int NT = K/32;  // 32
  // prologue: stage tiles 0,1,2 (12 loads); wait until tile 0 landed (8 newest in flight)
  stage4(gA,      gB,      As[0] + wv*1024, Bs[0] + wv*1024, row16);
  stage4(gA + 32, gB + 32, As[1] + wv*1024, Bs[1] + wv*1024, row16);
  stage4(gA + 64, gB + 64, As[2] + wv*1024, Bs[2] + wv*1024, row16);
  asm volatile("s_waitcnt vmcnt(8)" ::: "memory");
  __builtin_amdgcn_s_barrier();
  __builtin_amdgcn_sched_barrier(0);

  for (int t=0; t<NT; ++t){
    int k3 = (t+3)*32;
    if (k3 < K)
      stage4(gA + k3, gB + k3, As[(t+3)&3] + wv*1024, Bs[(t+3)&3] + wv*1024, row16);
    const char* AsB = (const char*)As[t&3];
    const char* BsB = (const char*)Bs[t&3];
    bf16x8 af[4], bfr[4];
    #pragma unroll
    for (int i=0;i<4;i++){
      af[i]  = *(const bf16x8*)(AsB + aoff[i]);
      bfr[i] = *(const bf16x8*)(BsB + boff[i]);
    }
    #pragma unroll
    for (int i=0;i<4;i++)
      #pragma unroll
      for (int j=0;j<4;j++)
        acc[i][j] = mfma16(af[i], bfr[j], acc[i][j]);
    if (t < NT-1){
      if (t < NT-3)       asm volatile("s_waitcnt vmcnt(8)" ::: "memory");
      else if (t == NT-3) asm volatile("s_waitcnt vmcnt(4)" ::: "memory");
      else                asm volatile("s_waitcnt vmcnt(0)" ::: "memory");
      __builtin_amdgcn_s_barrier();
      __builtin_amdgcn_sched_barrier(0);
    }
  }

  #pragma unroll
  for (int i=0;i<4;i++){
    #pragma unroll
    for (int j=0;j<4;j++){
      if constexpr (MODE == 0){
        #pragma unroll
        for (int e=0;e<4;e++){
          int row = m0 + wm*64 + i*16 + lg*4 + e;
          int col = n0 + wn*64 + j*16 + lr;
          Cf[(size_t)row*N + col] = acc[i][j][e];
        }
      } else {
        int col  = n0 + wn*64 + j*16 + lr;
        int rowb = m0 + wm*64 + i*16 + lg*4;
        if (col < 2048){
          #pragma unroll
          for (int e=0;e<4;e++){
            int row = rowb + e;
            float val = acc[i][j][e];
            float partner = __shfl_xor(val, 1);
            int s = row&4095;
            int w = s>>9, ii = s&511, bwi = (row>>12)*8 + w;
            int hh = (col>>6)&15, dh = col&63;
            int fp = dh>>1;
            float cs = cosT[s*32+fp], sn = sinT[s*32+fp];
            float rot = (col&1) ? fmaf(val,cs, partner*sn) : fmaf(val,cs, -partner*sn);
            if (col < 1024) Qb[((size_t)(bwi*HEADS+hh)*SEGL + ii)*DIMH + dh] = f2bf(rot);
            else            Kb[((size_t)(bwi*HEADS+hh)*KVLEN + NPM + ii)*DIMH + dh] = f2bf(rot);
          }
        } else {
          #pragma unroll
          for (int e=0;e<4;e++){
            int row = rowb + e;
            float val = acc[i][j][e];
            int s = row&4095;
            int w = s>>9, ii = s&511, bwi = (row>>12)*8 + w;
            int hh = (col>>6)&15, dh = col&63;
            Vb[((size_t)(bwi*HEADS+hh)*512 + ii)*DIMH + dh] = f2bf(val);
            origv[((size_t)((row>>12)*HEADS+hh)*NS + s)*DIMH + dh] = val;
          }
        }
      }
    }
  }
}

__global__ __launch_bounds__(256) void gemm_qkv_k(const unsigned short* __restrict__ A,
    const unsigned short* __restrict__ Bt,
    unsigned short* __restrict__ Qb, unsigned short* __restrict__ Kb, unsigned short* __restrict__ Vb,
    float* __restrict__ origv, const float* __restrict__ cosT, const float* __restrict__ sinT){
  gemm_body<1>(A, Bt, nullptr, Qb, Kb, Vb, origv, cosT, sinT, NQKV, 1024);
}

__global__ __launch_bounds__(256) void gemm_out_k(const unsigned short* __restrict__ A,
    const unsigned short* __restrict__ Bt, float* __restrict__ Cf){
  gemm_body<0>(A, Bt, Cf, nullptr, nullptr, nullptr, nullptr, nullptr, nullptr, 1024, 1024);
}

// ---------------- attention (unchanged from r9 passing build) ----------------
__global__ __launch_bounds__(256) void attn_k(const unsigned short* __restrict__ Qb,
    const unsigned short* __restrict__ Kb, const unsigned short* __restrict__ VbT,
    unsigned short* __restrict__ att){
  int qt = blockIdx.x, h = blockIdx.y, bw = blockIdx.z;
  int t = threadIdx.x, lane = t&63, wv = t>>6, lr = lane&15, lg = lane>>4;
  __shared__ __align__(16) unsigned short Ks[2][4096];
  __shared__ __align__(16) unsigned short Vs[2][4096];

  const unsigned short* Kbase = Kb  + (size_t)(bw*HEADS+h)*KVLEN*DIMH;
  const unsigned short* Vtb   = VbT + (size_t)(bw*HEADS+h)*DIMH*KVLEN;

  bf16x8 qf[2][2];
  #pragma unroll
  for (int ifr=0; ifr<2; ++ifr){
    const unsigned short* Qrow = Qb + ((size_t)((bw*HEADS+h)*SEGL) + qt*128 + wv*32 + ifr*16 + lr)*DIMH;
    #pragma unroll
    for (int kh=0; kh<2; ++kh){
      FragU f;
      f.q[0] = *(const uint64_t*)(Qrow + kh*32 + lg*4);
      f.q[1] = *(const uint64_t*)(Qrow + kh*32 + 16 + lg*4);
      qf[ifr][kh] = f.v;
    }
  }

  int rls[2], xsw[2];
  #pragma unroll
  for (int k2=0;k2<2;k2++){
    rls[k2] = wv*16 + k2*8 + (lane>>3);
    xsw[k2] = ((lane&7)*16) ^ ((rls[k2]&7)<<4);
  }

  #define STAGE_KV(buf, j0_) do { \
    int xm_ = ((j0_) == 512) ? 31 : 127; \
    _Pragma("unroll") \
    for (int k2=0;k2<2;k2++){ \
      int jr = (j0_) + rls[k2]; if (jr>527) jr=527; \
      gl_lds16((const unsigned short*)((const char*)Kbase + (size_t)jr*128 + xsw[k2]), \
               Ks[buf] + wv*1024 + k2*512); \
      gl_lds16((const unsigned short*)((const char*)Vtb + (size_t)rls[k2]*(KVLEN*2) + (size_t)(j0_)*2 + (xsw[k2] & xm_)), \
               Vs[buf] + wv*1024 + k2*512); \
    } \
  } while(0)

  const float NEG = -3.0e38f;
  float m[2]  = {NEG, NEG};
  float lsum[2] = {0.f, 0.f};
  f32x4 o[4][2];
  f32x4 z = {0.f,0.f,0.f,0.f};
  #pragma unroll
  for (int df=0; df<4; ++df){ o[df][0]=z; o[df][1]=z; }

  int ntiles = (qt*128 + 207)>>6; if (ntiles>9) ntiles=9;
  int swzK = (lr&7)<<4;

  STAGE_KV(0, 0);
  __syncthreads();

  int cur = 0;
  for (int jt=0; jt<ntiles; ++jt){
    int j0 = jt*64;
    if (jt+1 < ntiles) STAGE_KV(cur^1, j0+64);

    const char* KsB = (const char*)Ks[cur];
    f32x4 s[2][4];
    #pragma unroll
    for (int ifr=0; ifr<2; ++ifr)
      #pragma unroll
      for (int jf=0; jf<4; ++jf) s[ifr][jf] = z;
    #pragma unroll
    for (int jf=0; jf<4; ++jf){
      int rowb = (jf*16 + lr)*128;
      #pragma unroll
      for (int kh=0; kh<2; ++kh){
        FragU kf;
        kf.q[0] = *(const uint64_t*)(KsB + rowb + ((kh*64      + lg*8) ^ swzK));
        kf.q[1] = *(const uint64_t*)(KsB + rowb + ((kh*64 + 32 + lg*8) ^ swzK));
        s[0][jf] = mfma16(kf.v, qf[0][kh], s[0][jf]);
        s[1][jf] = mfma16(kf.v, qf[1][kh], s[1][jf]);
      }
    }

    float alpha[2];
    #pragma unroll
    for (int ifr=0; ifr<2; ++ifr){
      int iglob = qt*128 + wv*32 + ifr*16 + lr;
      float mt = NEG;
      #pragma unroll
      for (int jf=0; jf<4; ++jf){
        #pragma unroll
        for (int e=0;e<4;e++){
          int jl = j0 + jf*16 + lg*4 + e;
          bool ok = (jl < KVLEN) && (jl - NPM <= iglob);
          float v = ok ? s[ifr][jf][e]*0.125f : NEG;
          s[ifr][jf][e] = v;
          mt = fmaxf(mt, v);
        }
      }
      mt = fmaxf(mt, __shfl_xor(mt, 16));
      mt = fmaxf(mt, __shfl_xor(mt, 32));
      float mn = fmaxf(m[ifr], mt);
      alpha[ifr] = __expf(m[ifr]-mn);
      m[ifr] = mn;
      float ps = 0.f;
      #pragma unroll
      for (int jf=0; jf<4; ++jf){
        #pragma unroll
        for (int e=0;e<4;e++){
          float p = __expf(s[ifr][jf][e] - mn);
          s[ifr][jf][e] = p;
          ps += p;
        }
      }
      ps += __shfl_xor(ps, 16);
      ps += __shfl_xor(ps, 32);
      lsum[ifr] = lsum[ifr]*alpha[ifr] + ps;
    }

    bf16x8 pa[2][2];
    #pragma unroll
    for (int ifr=0; ifr<2; ++ifr){
      #pragma unroll
      for (int kh=0; kh<2; ++kh){
        FragU f;
        #pragma unroll
        for (int e=0;e<4;e++){
          f.u[e]   = f2bf(s[ifr][2*kh  ][e]);
          f.u[4+e] = f2bf(s[ifr][2*kh+1][e]);
        }
        pa[ifr][kh] = f.v;
      }
    }

    #pragma unroll
    for (int ifr=0; ifr<2; ++ifr){
      float ae[4];
      #pragma unroll
      for (int e=0;e<4;e++) ae[e] = __shfl(alpha[ifr], lg*4+e, 16);
      #pragma unroll
      for (int df=0; df<4; ++df)
        #pragma unroll
        for (int e=0;e<4;e++) o[df][ifr][e] *= ae[e];
    }

    const char* VsB = (const char*)Vs[cur];
    #pragma unroll
    for (int df=0; df<4; ++df){
      int vrow = (df*16 + lr)*128;
      FragU v0, v1;
      v0.q[0] = *(const uint64_t*)(VsB + vrow + ((      lg*8) ^ swzK));
      v0.q[1] = *(const uint64_t*)(VsB + vrow + ((32  + lg*8) ^ swzK));
      v1.q[0] = *(const uint64_t*)(VsB + vrow + ((64  + lg*8) ^ swzK));
      v1.q[1] = *(const uint64_t*)(VsB + vrow + ((96  + lg*8) ^ swzK));
      o[df][0] = mfma16(pa[0][0], v0.v, o[df][0]);
      o[df][0] = mfma16(pa[0][1], v1.v, o[df][0]);
      o[df][1] = mfma16(pa[1][0], v0.v, o[df][1]);
      o[df][1] = mfma16(pa[1][1], v1.v, o[df][1]);
    }

    __syncthreads();
    cur ^= 1;
  }

  #pragma unroll
  for (int ifr=0; ifr<2; ++ifr){
    float inv = 1.0f / lsum[ifr];
    float il[4];
    #pragma unroll
    for (int e=0;e<4;e++) il[e] = __shfl(inv, lg*4+e, 16);
    #pragma unroll
    for (int e=0;e<4;e++){
      int row = bw*SEGL + qt*128 + wv*32 + ifr*16 + lg*4 + e;
      #pragma unroll
      for (int df=0; df<4; ++df)
        att[(size_t)row*1024 + h*64 + df*16 + lr] = f2bf(o[df][ifr][e]*il[e]);
    }
  }
  #undef STAGE_KV
}

extern "C" void kernel_launch(void* const* d_in, const int* in_sizes, int n_in,
                              void* d_out, int out_size, void* d_ws, size_t ws_size,
                              hipStream_t stream) {
  const float* seq  = (const float*)d_in[0];
  const float* nw   = (const float*)d_in[1];
  const float* wqkv = (const float*)d_in[2];
  const float* wout = (const float*)d_in[3];
  const float* pmem = (const float*)d_in[4];
  float* out0  = (float*)d_out;
  float* origv = out0 + (size_t)MROWS*ND;

  char* ws = (char*)d_ws;
  unsigned short* xbf   = (unsigned short*)(ws + 0);          // 16,777,216
  unsigned short* wqkvT = (unsigned short*)(ws + 16777216);   //  6,291,456
  unsigned short* woutT = (unsigned short*)(ws + 23068672);   //  2,097,152
  float*          cosT  = (float*)(ws + 25165824);            //    524,288
  float*          sinT  = (float*)(ws + 25690112);            //    524,288
  unsigned short* Qb    = (unsigned short*)(ws + 26214400);   // 16,777,216
  unsigned short* Kb    = (unsigned short*)(ws + 42991616);   // 17,301,504
  unsigned short* VbT   = (unsigned short*)(ws + 60293120);   // 17,301,504 ([bwh][64][528])
  unsigned short* att   = (unsigned short*)(ws + 77594624);   // 16,777,216
  unsigned short* Vb    = att;  // [bwh][512][64] temp; dead before attn writes att

  rope_table_k<<<dim3(512), dim3(256), 0, stream>>>(cosT, sinT);
  rmsnorm_k<<<dim3(MROWS), dim3(256), 0, stream>>>(seq, nw, xbf);
  tcast_k<<<dim3(NQKV/32, 1024/32), dim3(256), 0, stream>>>(wqkv, wqkvT, 1024, NQKV);
  tcast_k<<<dim3(1024/32, 1024/32), dim3(256), 0, stream>>>(wout, woutT, 1024, 1024);
  pmem_fill_k<<<dim3(1024), dim3(256), 0, stream>>>(pmem, Kb, VbT);
  gemm_qkv_k<<<dim3(NQKV/128, MROWS/128), dim3(256), 0, stream>>>(
      xbf, wqkvT, Qb, Kb, Vb, origv, cosT, sinT);
  vtrans_k<<<dim3(8, NBW*HEADS), dim3(256), 0, stream>>>(Vb, VbT);
  attn_k<<<dim3(4, 16, 16), dim3(256), 0, stream>>>(Qb, Kb, VbT, att);
  gemm_out_k<<<dim3(1024/128, MROWS/128), dim3(256), 0, stream>>>(att, woutT, out0);
}

// Round 12
// 212.445 us; speedup vs baseline: 1.4145x; 1.1400x over previous
//
#include <hip/hip_runtime.h>
#include <hip/hip_bf16.h>
#include <stdint.h>

#define HEADS 16
#define DIMH 64
#define SEGL 512
#define NPM 16
#define NB 2
#define NS 4096
#define ND 1024
#define NW 8
#define NBW 16
#define KVLEN 528
#define NQKV 3072
#define MROWS 8192
#define RMS_EPS 1.1920928955078125e-07f

typedef __attribute__((ext_vector_type(8))) short bf16x8;
typedef __attribute__((ext_vector_type(4))) float f32x4;
typedef __attribute__((ext_vector_type(8))) unsigned short u16x8;

union FragU { bf16x8 v; uint64_t q[2]; unsigned short u[8]; };

__device__ inline unsigned short f2bf(float x){
  __hip_bfloat16 b = __float2bfloat16(x);
  return __builtin_bit_cast(unsigned short, b);
}

__device__ inline f32x4 mfma16(bf16x8 a, bf16x8 b, f32x4 c){
  return __builtin_amdgcn_mfma_f32_16x16x32_bf16(a, b, c, 0, 0, 0);
}

// async global->LDS, 16B per lane; LDS dest = wave-uniform base + lane*16
__device__ __forceinline__ void gl_lds16(const unsigned short* g, unsigned short* l){
  __builtin_amdgcn_global_load_lds(
    (const __attribute__((address_space(1))) unsigned int*)g,
    (__attribute__((address_space(3))) unsigned int*)l, 16, 0, 0);
}

// ---------------- rope table ----------------
__global__ void rope_table_k(float* __restrict__ cosT, float* __restrict__ sinT){
  int id = blockIdx.x*256 + threadIdx.x;
  if (id >= NS*32) return;
  int p = id & 31, s = id >> 5;
  float inv = powf(10000.0f, -(float)p * (1.0f/32.0f));
  float a = (float)s * inv;
  cosT[id] = cosf(a);
  sinT[id] = sinf(a);
}

// ---------------- rmsnorm + cast ----------------
__global__ __launch_bounds__(256) void rmsnorm_k(const float* __restrict__ seq, const float* __restrict__ nw,
                                                 unsigned short* __restrict__ xo){
  int r = blockIdx.x, t = threadIdx.x;
  const float4 v = ((const float4*)(seq + (size_t)r*ND))[t];
  float ss = v.x*v.x + v.y*v.y + v.z*v.z + v.w*v.w;
  #pragma unroll
  for (int off=32; off; off>>=1) ss += __shfl_xor(ss, off);
  __shared__ float red[4];
  if ((t&63)==0) red[t>>6] = ss;
  __syncthreads();
  float scale = rsqrtf((red[0]+red[1]+red[2]+red[3])*(1.0f/(float)ND) + RMS_EPS);
  const float4 w = ((const float4*)nw)[t];
  ushort4 o;
  o.x = f2bf(v.x*scale*w.x);
  o.y = f2bf(v.y*scale*w.y);
  o.z = f2bf(v.z*scale*w.z);
  o.w = f2bf(v.w*scale*w.w);
  ((ushort4*)xo)[(size_t)r*256 + t] = o;
}

// ---------------- transpose + cast weights ----------------
__global__ __launch_bounds__(256) void tcast_k(const float* __restrict__ in, unsigned short* __restrict__ out,
                                               int R, int C){
  __shared__ float tile[32][33];
  int c0 = blockIdx.x*32, r0 = blockIdx.y*32;
  int tx = threadIdx.x & 31, ty = threadIdx.x >> 5;
  #pragma unroll
  for (int i=0;i<4;i++) tile[ty+8*i][tx] = in[(size_t)(r0+ty+8*i)*C + c0+tx];
  __syncthreads();
  #pragma unroll
  for (int i=0;i<4;i++) out[(size_t)(c0+ty+8*i)*R + r0+tx] = f2bf(tile[tx][ty+8*i]);
}

// ---------------- pmem prefix fill ----------------
__global__ void pmem_fill_k(const float* __restrict__ pmem, unsigned short* __restrict__ Kb,
                            unsigned short* __restrict__ VbT){
  int id = blockIdx.x*256 + threadIdx.x;
  if (id >= NBW*HEADS*NPM*DIMH) return;
  int d = id & 63, j = (id>>6)&15, h = (id>>10)&15, bw = id>>14;
  size_t srcK = ((size_t)h*NPM + j)*DIMH + d;
  Kb[((size_t)(bw*HEADS+h)*KVLEN + j)*DIMH + d] = f2bf(pmem[srcK]);
  VbT[((size_t)(bw*HEADS+h)*DIMH + d)*KVLEN + j] = f2bf(pmem[(size_t)HEADS*NPM*DIMH + srcK]);
}

// ---------------- Vb[bwh][512][64] -> VbT[bwh][64][528] ----------------
__global__ __launch_bounds__(256) void vtrans_k(const unsigned short* __restrict__ Vb,
                                                unsigned short* __restrict__ VbT){
  __shared__ unsigned short T[64][72];
  int jt = blockIdx.x, bwh = blockIdx.y, t = threadIdx.x;
  int r = t>>2, c = t&3;
  int j0 = jt*64;
  const unsigned short* src = Vb + ((size_t)bwh*512 + j0 + r)*DIMH + c*16;
  *(u16x8*)&T[r][c*16]     = *(const u16x8*)(src);
  *(u16x8*)&T[r][c*16 + 8] = *(const u16x8*)(src + 8);
  __syncthreads();
  u16x8 outv, outv2;
  #pragma unroll
  for (int k=0;k<8;k++) outv[k] = T[c*16+k][r];
  #pragma unroll
  for (int k=0;k<8;k++) outv2[k] = T[c*16+8+k][r];
  *(u16x8*)&VbT[((size_t)bwh*DIMH + r)*KVLEN + NPM + j0 + c*16] = outv;
  *(u16x8*)&VbT[((size_t)bwh*DIMH + r)*KVLEN + NPM + j0 + c*16 + 8] = outv2;
}

// ---------------- GEMM body: 2-phase dbuf, 8 waves (512 thr), 128x128 tile ----------------
// Per-wave output 32x64 (acc[2][4]); wm=wv&3 (M slice of 32), wn=wv>>2 (N slice of 64).
// Staging: wave wv stages A rows [wv*16,wv*16+16) and B rows [wv*16,wv*16+16), one
// gl_lds16 each (lane l -> row wv*16+(l>>2), 16B chunk (l&3); dest wv*512 + l*8 shorts).
// MODE 0: write f32 C. MODE 1: fused qkv epilogue (rope + scatter; V row-major + origv).
template<int MODE>
__device__ __forceinline__ void gemm_body(const unsigned short* __restrict__ A,
    const unsigned short* __restrict__ Bt, float* __restrict__ Cf,
    unsigned short* __restrict__ Qb, unsigned short* __restrict__ Kb, unsigned short* __restrict__ Vb,
    float* __restrict__ origv, const float* __restrict__ cosT, const float* __restrict__ sinT,
    int N, int K){
  __shared__ __align__(16) unsigned short As[2][4096];  // [buf][128][32]
  __shared__ __align__(16) unsigned short Bs[2][4096];
  int t0 = threadIdx.x; int lane = t0&63; int wv = t0>>6; int lr = lane&15; int lg = lane>>4;
  int wm = wv&3, wn = wv>>2;
  int m0 = blockIdx.y*128, n0 = blockIdx.x*128;

  f32x4 acc[2][4];
  f32x4 z = {0.f,0.f,0.f,0.f};
  #pragma unroll
  for (int i=0;i<2;i++)
    #pragma unroll
    for (int j=0;j<4;j++) acc[i][j] = z;

  const unsigned short* gA = A  + (size_t)(m0 + wv*16 + (lane>>2))*K + (lane&3)*8;
  const unsigned short* gB = Bt + (size_t)(n0 + wv*16 + (lane>>2))*K + (lane&3)*8;

  int aoff[2], boff[4];
  #pragma unroll
  for (int i=0;i<2;i++) aoff[i] = (wm*32 + i*16 + lr)*64 + lg*16;
  #pragma unroll
  for (int j=0;j<4;j++) boff[j] = (wn*64 + j*16 + lr)*64 + lg*16;

  // prologue: stage tile 0
  gl_lds16(gA, As[0] + wv*512);
  gl_lds16(gB, Bs[0] + wv*512);
  __syncthreads();

  int cur = 0;
  for (int k0=0; k0<K; k0+=32){
    int nk = k0 + 32;
    if (nk < K){   // issue next tile's loads BEFORE consuming current
      gl_lds16(gA + nk, As[cur^1] + wv*512);
      gl_lds16(gB + nk, Bs[cur^1] + wv*512);
    }
    const char* AsB = (const char*)As[cur];
    const char* BsB = (const char*)Bs[cur];
    bf16x8 af[2], bfr[4];
    #pragma unroll
    for (int i=0;i<2;i++) af[i]  = *(const bf16x8*)(AsB + aoff[i]);
    #pragma unroll
    for (int j=0;j<4;j++) bfr[j] = *(const bf16x8*)(BsB + boff[j]);
    #pragma unroll
    for (int i=0;i<2;i++)
      #pragma unroll
      for (int j=0;j<4;j++)
        acc[i][j] = mfma16(af[i], bfr[j], acc[i][j]);
    __syncthreads();   // drains my vmcnt (next tile landed) + all waves done reading cur
    cur ^= 1;
  }

  #pragma unroll
  for (int i=0;i<2;i++){
    #pragma unroll
    for (int j=0;j<4;j++){
      if constexpr (MODE == 0){
        #pragma unroll
        for (int e=0;e<4;e++){
          int row = m0 + wm*32 + i*16 + lg*4 + e;
          int col = n0 + wn*64 + j*16 + lr;
          Cf[(size_t)row*N + col] = acc[i][j][e];
        }
      } else {
        int col  = n0 + wn*64 + j*16 + lr;
        int rowb = m0 + wm*32 + i*16 + lg*4;
        if (col < 2048){
          #pragma unroll
          for (int e=0;e<4;e++){
            int row = rowb + e;
            float val = acc[i][j][e];
            float partner = __shfl_xor(val, 1);
            int s = row&4095;
            int w = s>>9, ii = s&511, bwi = (row>>12)*8 + w;
            int hh = (col>>6)&15, dh = col&63;
            int fp = dh>>1;
            float cs = cosT[s*32+fp], sn = sinT[s*32+fp];
            float rot = (col&1) ? fmaf(val,cs, partner*sn) : fmaf(val,cs, -partner*sn);
            if (col < 1024) Qb[((size_t)(bwi*HEADS+hh)*SEGL + ii)*DIMH + dh] = f2bf(rot);
            else            Kb[((size_t)(bwi*HEADS+hh)*KVLEN + NPM + ii)*DIMH + dh] = f2bf(rot);
          }
        } else {
          #pragma unroll
          for (int e=0;e<4;e++){
            int row = rowb + e;
            float val = acc[i][j][e];
            int s = row&4095;
            int w = s>>9, ii = s&511, bwi = (row>>12)*8 + w;
            int hh = (col>>6)&15, dh = col&63;
            Vb[((size_t)(bwi*HEADS+hh)*512 + ii)*DIMH + dh] = f2bf(val);
            origv[((size_t)((row>>12)*HEADS+hh)*NS + s)*DIMH + dh] = val;
          }
        }
      }
    }
  }
}

__global__ __launch_bounds__(512) void gemm_qkv_k(const unsigned short* __restrict__ A,
    const unsigned short* __restrict__ Bt,
    unsigned short* __restrict__ Qb, unsigned short* __restrict__ Kb, unsigned short* __restrict__ Vb,
    float* __restrict__ origv, const float* __restrict__ cosT, const float* __restrict__ sinT){
  gemm_body<1>(A, Bt, nullptr, Qb, Kb, Vb, origv, cosT, sinT, NQKV, 1024);
}

__global__ __launch_bounds__(512) void gemm_out_k(const unsigned short* __restrict__ A,
    const unsigned short* __restrict__ Bt, float* __restrict__ Cf){
  gemm_body<0>(A, Bt, Cf, nullptr, nullptr, nullptr, nullptr, nullptr, nullptr, 1024, 1024);
}

// ---------------- attention (unchanged from r9 passing build) ----------------
__global__ __launch_bounds__(256) void attn_k(const unsigned short* __restrict__ Qb,
    const unsigned short* __restrict__ Kb, const unsigned short* __restrict__ VbT,
    unsigned short* __restrict__ att){
  int qt = blockIdx.x, h = blockIdx.y, bw = blockIdx.z;
  int t = threadIdx.x, lane = t&63, wv = t>>6, lr = lane&15, lg = lane>>4;
  __shared__ __align__(16) unsigned short Ks[2][4096];
  __shared__ __align__(16) unsigned short Vs[2][4096];

  const unsigned short* Kbase = Kb  + (size_t)(bw*HEADS+h)*KVLEN*DIMH;
  const unsigned short* Vtb   = VbT + (size_t)(bw*HEADS+h)*DIMH*KVLEN;

  bf16x8 qf[2][2];
  #pragma unroll
  for (int ifr=0; ifr<2; ++ifr){
    const unsigned short* Qrow = Qb + ((size_t)((bw*HEADS+h)*SEGL) + qt*128 + wv*32 + ifr*16 + lr)*DIMH;
    #pragma unroll
    for (int kh=0; kh<2; ++kh){
      FragU f;
      f.q[0] = *(const uint64_t*)(Qrow + kh*32 + lg*4);
      f.q[1] = *(const uint64_t*)(Qrow + kh*32 + 16 + lg*4);
      qf[ifr][kh] = f.v;
    }
  }

  int rls[2], xsw[2];
  #pragma unroll
  for (int k2=0;k2<2;k2++){
    rls[k2] = wv*16 + k2*8 + (lane>>3);
    xsw[k2] = ((lane&7)*16) ^ ((rls[k2]&7)<<4);
  }

  #define STAGE_KV(buf, j0_) do { \
    int xm_ = ((j0_) == 512) ? 31 : 127; \
    _Pragma("unroll") \
    for (int k2=0;k2<2;k2++){ \
      int jr = (j0_) + rls[k2]; if (jr>527) jr=527; \
      gl_lds16((const unsigned short*)((const char*)Kbase + (size_t)jr*128 + xsw[k2]), \
               Ks[buf] + wv*1024 + k2*512); \
      gl_lds16((const unsigned short*)((const char*)Vtb + (size_t)rls[k2]*(KVLEN*2) + (size_t)(j0_)*2 + (xsw[k2] & xm_)), \
               Vs[buf] + wv*1024 + k2*512); \
    } \
  } while(0)

  const float NEG = -3.0e38f;
  float m[2]  = {NEG, NEG};
  float lsum[2] = {0.f, 0.f};
  f32x4 o[4][2];
  f32x4 z = {0.f,0.f,0.f,0.f};
  #pragma unroll
  for (int df=0; df<4; ++df){ o[df][0]=z; o[df][1]=z; }

  int ntiles = (qt*128 + 207)>>6; if (ntiles>9) ntiles=9;
  int swzK = (lr&7)<<4;

  STAGE_KV(0, 0);
  __syncthreads();

  int cur = 0;
  for (int jt=0; jt<ntiles; ++jt){
    int j0 = jt*64;
    if (jt+1 < ntiles) STAGE_KV(cur^1, j0+64);

    const char* KsB = (const char*)Ks[cur];
    f32x4 s[2][4];
    #pragma unroll
    for (int ifr=0; ifr<2; ++ifr)
      #pragma unroll
      for (int jf=0; jf<4; ++jf) s[ifr][jf] = z;
    #pragma unroll
    for (int jf=0; jf<4; ++jf){
      int rowb = (jf*16 + lr)*128;
      #pragma unroll
      for (int kh=0; kh<2; ++kh){
        FragU kf;
        kf.q[0] = *(const uint64_t*)(KsB + rowb + ((kh*64      + lg*8) ^ swzK));
        kf.q[1] = *(const uint64_t*)(KsB + rowb + ((kh*64 + 32 + lg*8) ^ swzK));
        s[0][jf] = mfma16(kf.v, qf[0][kh], s[0][jf]);
        s[1][jf] = mfma16(kf.v, qf[1][kh], s[1][jf]);
      }
    }

    float alpha[2];
    #pragma unroll
    for (int ifr=0; ifr<2; ++ifr){
      int iglob = qt*128 + wv*32 + ifr*16 + lr;
      float mt = NEG;
      #pragma unroll
      for (int jf=0; jf<4; ++jf){
        #pragma unroll
        for (int e=0;e<4;e++){
          int jl = j0 + jf*16 + lg*4 + e;
          bool ok = (jl < KVLEN) && (jl - NPM <= iglob);
          float v = ok ? s[ifr][jf][e]*0.125f : NEG;
          s[ifr][jf][e] = v;
          mt = fmaxf(mt, v);
        }
      }
      mt = fmaxf(mt, __shfl_xor(mt, 16));
      mt = fmaxf(mt, __shfl_xor(mt, 32));
      float mn = fmaxf(m[ifr], mt);
      alpha[ifr] = __expf(m[ifr]-mn);
      m[ifr] = mn;
      float ps = 0.f;
      #pragma unroll
      for (int jf=0; jf<4; ++jf){
        #pragma unroll
        for (int e=0;e<4;e++){
          float p = __expf(s[ifr][jf][e] - mn);
          s[ifr][jf][e] = p;
          ps += p;
        }
      }
      ps += __shfl_xor(ps, 16);
      ps += __shfl_xor(ps, 32);
      lsum[ifr] = lsum[ifr]*alpha[ifr] + ps;
    }

    bf16x8 pa[2][2];
    #pragma unroll
    for (int ifr=0; ifr<2; ++ifr){
      #pragma unroll
      for (int kh=0; kh<2; ++kh){
        FragU f;
        #pragma unroll
        for (int e=0;e<4;e++){
          f.u[e]   = f2bf(s[ifr][2*kh  ][e]);
          f.u[4+e] = f2bf(s[ifr][2*kh+1][e]);
        }
        pa[ifr][kh] = f.v;
      }
    }

    #pragma unroll
    for (int ifr=0; ifr<2; ++ifr){
      float ae[4];
      #pragma unroll
      for (int e=0;e<4;e++) ae[e] = __shfl(alpha[ifr], lg*4+e, 16);
      #pragma unroll
      for (int df=0; df<4; ++df)
        #pragma unroll
        for (int e=0;e<4;e++) o[df][ifr][e] *= ae[e];
    }

    const char* VsB = (const char*)Vs[cur];
    #pragma unroll
    for (int df=0; df<4; ++df){
      int vrow = (df*16 + lr)*128;
      FragU v0, v1;
      v0.q[0] = *(const uint64_t*)(VsB + vrow + ((      lg*8) ^ swzK));
      v0.q[1] = *(const uint64_t*)(VsB + vrow + ((32  + lg*8) ^ swzK));
      v1.q[0] = *(const uint64_t*)(VsB + vrow + ((64  + lg*8) ^ swzK));
      v1.q[1] = *(const uint64_t*)(VsB + vrow + ((96  + lg*8) ^ swzK));
      o[df][0] = mfma16(pa[0][0], v0.v, o[df][0]);
      o[df][0] = mfma16(pa[0][1], v1.v, o[df][0]);
      o[df][1] = mfma16(pa[1][0], v0.v, o[df][1]);
      o[df][1] = mfma16(pa[1][1], v1.v, o[df][1]);
    }

    __syncthreads();
    cur ^= 1;
  }

  #pragma unroll
  for (int ifr=0; ifr<2; ++ifr){
    float inv = 1.0f / lsum[ifr];
    float il[4];
    #pragma unroll
    for (int e=0;e<4;e++) il[e] = __shfl(inv, lg*4+e, 16);
    #pragma unroll
    for (int e=0;e<4;e++){
      int row = bw*SEGL + qt*128 + wv*32 + ifr*16 + lg*4 + e;
      #pragma unroll
      for (int df=0; df<4; ++df)
        att[(size_t)row*1024 + h*64 + df*16 + lr] = f2bf(o[df][ifr][e]*il[e]);
    }
  }
  #undef STAGE_KV
}

extern "C" void kernel_launch(void* const* d_in, const int* in_sizes, int n_in,
                              void* d_out, int out_size, void* d_ws, size_t ws_size,
                              hipStream_t stream) {
  const float* seq  = (const float*)d_in[0];
  const float* nw   = (const float*)d_in[1];
  const float* wqkv = (const float*)d_in[2];
  const float* wout = (const float*)d_in[3];
  const float* pmem = (const float*)d_in[4];
  float* out0  = (float*)d_out;
  float* origv = out0 + (size_t)MROWS*ND;

  char* ws = (char*)d_ws;
  unsigned short* xbf   = (unsigned short*)(ws + 0);          // 16,777,216
  unsigned short* wqkvT = (unsigned short*)(ws + 16777216);   //  6,291,456
  unsigned short* woutT = (unsigned short*)(ws + 23068672);   //  2,097,152
  float*          cosT  = (float*)(ws + 25165824);            //    524,288
  float*          sinT  = (float*)(ws + 25690112);            //    524,288
  unsigned short* Qb    = (unsigned short*)(ws + 26214400);   // 16,777,216
  unsigned short* Kb    = (unsigned short*)(ws + 42991616);   // 17,301,504
  unsigned short* VbT   = (unsigned short*)(ws + 60293120);   // 17,301,504 ([bwh][64][528])
  unsigned short* att   = (unsigned short*)(ws + 77594624);   // 16,777,216
  unsigned short* Vb    = att;  // [bwh][512][64] temp; dead before attn writes att

  rope_table_k<<<dim3(512), dim3(256), 0, stream>>>(cosT, sinT);
  rmsnorm_k<<<dim3(MROWS), dim3(256), 0, stream>>>(seq, nw, xbf);
  tcast_k<<<dim3(NQKV/32, 1024/32), dim3(256), 0, stream>>>(wqkv, wqkvT, 1024, NQKV);
  tcast_k<<<dim3(1024/32, 1024/32), dim3(256), 0, stream>>>(wout, woutT, 1024, 1024);
  pmem_fill_k<<<dim3(1024), dim3(256), 0, stream>>>(pmem, Kb, VbT);
  gemm_qkv_k<<<dim3(NQKV/128, MROWS/128), dim3(512), 0, stream>>>(
      xbf, wqkvT, Qb, Kb, Vb, origv, cosT, sinT);
  vtrans_k<<<dim3(8, NBW*HEADS), dim3(256), 0, stream>>>(Vb, VbT);
  attn_k<<<dim3(4, 16, 16), dim3(256), 0, stream>>>(Qb, Kb, VbT, att);
  gemm_out_k<<<dim3(1024/128, MROWS/128), dim3(512), 0, stream>>>(att, woutT, out0);
}